// Round 6
// baseline (98.376 us; speedup 1.0000x reference)
//
#include <hip/hip_runtime.h>
#include <hip/hip_bf16.h>

#define N 8192
#define D 512
#define BT 256          // tile: BM = BN = 256
#define BK 64
#define NCB (N / BT)    // 32 column blocks
#define NKT (D / BK)    // 8 K tiles
#define NTRI (NCB * (NCB + 1) / 2)  // 528 upper-triangle blocks
#define INVT 14.285714285714286f

typedef __attribute__((ext_vector_type(8))) short bf16x8;
typedef __attribute__((ext_vector_type(4))) float f32x4;
typedef __attribute__((ext_vector_type(8))) unsigned short u16x8;

__device__ __forceinline__ unsigned short f2bf(float f) {
  __hip_bfloat16 h = __float2bfloat16(f);
  return *reinterpret_cast<unsigned short*>(&h);
}

// ---------------- kernel 1: L2-normalize rows, cast to bf16 ----------------
__global__ __launch_bounds__(256) void k_normalize(const float* __restrict__ x,
                                                   unsigned short* __restrict__ fb) {
  const int row = blockIdx.x * 4 + (threadIdx.x >> 6);
  const int lane = threadIdx.x & 63;
  const float* rp = x + (size_t)row * D + lane * 8;
  float4 v0 = *reinterpret_cast<const float4*>(rp);
  float4 v1 = *reinterpret_cast<const float4*>(rp + 4);
  float s = v0.x*v0.x + v0.y*v0.y + v0.z*v0.z + v0.w*v0.w
          + v1.x*v1.x + v1.y*v1.y + v1.z*v1.z + v1.w*v1.w;
  #pragma unroll
  for (int m = 1; m < 64; m <<= 1) s += __shfl_xor(s, m);
  float inv = 1.0f / fmaxf(sqrtf(s), 1e-12f);
  u16x8 o;
  o[0] = f2bf(v0.x*inv); o[1] = f2bf(v0.y*inv); o[2] = f2bf(v0.z*inv); o[3] = f2bf(v0.w*inv);
  o[4] = f2bf(v1.x*inv); o[5] = f2bf(v1.y*inv); o[6] = f2bf(v1.z*inv); o[7] = f2bf(v1.w*inv);
  *reinterpret_cast<u16x8*>(fb + (size_t)row * D + lane * 8) = o;
}

// ---------------- kernel 2: label histogram (pos counts) ----------------
__global__ __launch_bounds__(256) void k_hist(const int* __restrict__ labels,
                                              int* __restrict__ hist) {
  __shared__ int h[128];
  int tid = threadIdx.x;
  if (tid < 128) h[tid] = 0;
  __syncthreads();
  int i = blockIdx.x * 256 + tid;
  atomicAdd(&h[labels[i]], 1);
  __syncthreads();
  if (tid < 128 && h[tid]) atomicAdd(&hist[tid], h[tid]);
}

// ---------------- kernel 3: 8-phase 256^2 fused GEMM + exp/mask reductions ----
// n-major quadrants: each phase holds fb-full (32 regs) + one fa-pair (16,
// dies in-phase). R5 spilled because fa-half+fb0+fb2 (64) + compiler-sunk MFMA
// overlap with next phase's 12 ds_reads exceeded the 128-arch cap.
// Phase p computes acc[2p..2p+1][0..3] (16 MFMAs). Staging/WAR:
//   B-buf read only in P1/P5 -> free after P1/P5-end -> staged P2,P3 / P6,P7.
//   A-buf(b) read P1-P4 (b=0) / P5-P8 (b=1) -> A staged cross-buf at P1,P2 / P5,P6.
// Gates: vmcnt(4) at P4/P8-end (oldest 4 of 8 outstanding = the halves needed
// next), vmcnt(0) at last-iter P4 (only 4 outstanding = t7.A, all needed).
#define GL16(g, dstbytes) __builtin_amdgcn_global_load_lds( \
    (const __attribute__((address_space(1))) unsigned int*)(g), \
    (__attribute__((address_space(3))) unsigned int*)((char*)lds + (dstbytes)), 16, 0, 0)

__global__ __launch_bounds__(512, 2) void k_gemm(
    const unsigned short* __restrict__ fb_g, const int* __restrict__ labels,
    float* __restrict__ part_e, float* __restrict__ part_p) {
  __shared__ __align__(16) short lds[65536];   // 128 KiB: A bytes [0,64K), B [64K,128K)

  const int tid = threadIdx.x;
  const int lane = tid & 63;
  const int w = tid >> 6;
  const int wm = w >> 2, wn = w & 3;
  const int l15 = lane & 15;

  const int t = blockIdx.x;
  int bx = (int)((sqrtf(8.0f * (float)t + 1.0f) - 1.0f) * 0.5f);
  while ((bx + 1) * (bx + 2) / 2 <= t) ++bx;
  while (bx * (bx + 1) / 2 > t) --bx;
  const int by = t - bx * (bx + 1) / 2;
  const bool offdiag = (bx != by);
  const int rowA0 = by * BT, rowB0 = bx * BT;

  // ---- per-thread global stage pointers (source pre-swizzled k-slot) ----
  const int r0 = tid >> 3;                       // row within 64-row group
  const int sw = ((tid & 7) ^ (r0 & 7)) << 3;    // swizzled k element offset
  const unsigned short* pA0 = fb_g + (size_t)(rowA0 + r0) * D + sw;
  const unsigned short* pA1 = fb_g + (size_t)(rowA0 + 64 + r0) * D + sw;
  const unsigned short* pB0 = fb_g + (size_t)(rowB0 + r0) * D + sw;
  const unsigned short* pB1 = fb_g + (size_t)(rowB0 + 64 + r0) * D + sw;

#define STAGE_A(kt, h, DSTB) do { if ((kt) < NKT) { \
    GL16(pA0 + (h) * 128 * D + (kt) * BK, (DSTB) + w * 1024); \
    GL16(pA1 + (h) * 128 * D + (kt) * BK, (DSTB) + 8192 + w * 1024); } } while (0)
#define STAGE_B(kt, h, DSTB) do { if ((kt) < NKT) { \
    GL16(pB0 + (h) * 128 * D + (kt) * BK, (DSTB) + w * 1024); \
    GL16(pB1 + (h) * 128 * D + (kt) * BK, (DSTB) + 8192 + w * 1024); } } while (0)
  // LDS byte bases: A half(b,h) = (b*2+h)*16384 ; B half(b,h) = 65536 + (b*2+h)*16384

  // ---- per-thread LDS read vaddrs (ks = K-halfstep 0/1) ----
  const int hi16 = (lane >> 4) << 4;
  const int M = (l15 & 7) << 4;
  const char* ldsb = (const char*)lds;
  const char* vA_k0 = ldsb + wm * 16384 + l15 * 128 + ((0  + hi16) ^ M);
  const char* vA_k1 = ldsb + wm * 16384 + l15 * 128 + ((64 + hi16) ^ M);
  const char* vB_k0 = ldsb + 65536 + (wn >> 1) * 16384 + (wn & 1) * 8192 + l15 * 128 + ((0  + hi16) ^ M);
  const char* vB_k1 = ldsb + 65536 + (wn >> 1) * 16384 + (wn & 1) * 8192 + l15 * 128 + ((64 + hi16) ^ M);

#define RDA(dst, BUF, mloc, ks) \
    dst = *reinterpret_cast<const bf16x8*>(((ks) ? vA_k1 : vA_k0) + (BUF) * 32768 + (mloc) * 2048)
#define RDB(dst, BUF, nloc, ks) \
    dst = *reinterpret_cast<const bf16x8*>(((ks) ? vB_k1 : vB_k0) + (BUF) * 32768 + (nloc) * 2048)

  f32x4 acc[8][4] = {};

  // 16 MFMAs (2 m-rows x 4 n x 2 ks); trailing sched_barrier pins the cluster
  // before PHASE_END so it can't sink into the next phase's ds_reads (rule #18).
#define MFMA_PH(MB) do { \
    _Pragma("unroll") for (int ks = 0; ks < 2; ++ks) \
    _Pragma("unroll") for (int mm = 0; mm < 2; ++mm) \
    _Pragma("unroll") for (int nn = 0; nn < 4; ++nn) \
      acc[(MB) + mm][nn] = __builtin_amdgcn_mfma_f32_16x16x32_bf16( \
          fa[mm][ks], fb[nn][ks], acc[(MB) + mm][nn], 0, 0, 0); \
    __builtin_amdgcn_sched_barrier(0); } while (0)

#define PHASE_MID do { __builtin_amdgcn_s_barrier(); \
    asm volatile("s_waitcnt lgkmcnt(0)" ::: "memory"); \
    __builtin_amdgcn_sched_barrier(0); \
    __builtin_amdgcn_s_setprio(1); } while (0)
#define PHASE_END do { __builtin_amdgcn_s_setprio(0); \
    __builtin_amdgcn_s_barrier(); } while (0)
#define PHASE_END_V4 do { __builtin_amdgcn_s_setprio(0); \
    asm volatile("s_waitcnt vmcnt(4)" ::: "memory"); \
    __builtin_amdgcn_s_barrier(); } while (0)
#define PHASE_END_V0 do { __builtin_amdgcn_s_setprio(0); \
    asm volatile("s_waitcnt vmcnt(0)" ::: "memory"); \
    __builtin_amdgcn_s_barrier(); } while (0)

  bf16x8 fa[2][2], fb[4][2];

  // ---- prologue: t0 {B0,B1,A0,A1} -> buf0, t1 {B0,B1} -> buf1 (12 loads) ----
  STAGE_B(0, 0, 65536 + 0);
  STAGE_B(0, 1, 65536 + 16384);
  STAGE_A(0, 0, 0);
  STAGE_A(0, 1, 16384);
  STAGE_B(1, 0, 65536 + 32768);
  STAGE_B(1, 1, 65536 + 49152);
  asm volatile("s_waitcnt vmcnt(4)" ::: "memory");   // t0 fully resident
  __builtin_amdgcn_s_barrier();

#define ITERN(kb, kn, kn2, G4, G8) do { \
    /* P1: all fb(buf0) + fa m0-1 */ \
    RDA(fa[0][0], 0, 0, 0); RDA(fa[0][1], 0, 0, 1); \
    RDA(fa[1][0], 0, 1, 0); RDA(fa[1][1], 0, 1, 1); \
    RDB(fb[0][0], 0, 0, 0); RDB(fb[0][1], 0, 0, 1); \
    RDB(fb[1][0], 0, 1, 0); RDB(fb[1][1], 0, 1, 1); \
    RDB(fb[2][0], 0, 2, 0); RDB(fb[2][1], 0, 2, 1); \
    RDB(fb[3][0], 0, 3, 0); RDB(fb[3][1], 0, 3, 1); \
    STAGE_A(kb, 0, 32768); \
    PHASE_MID; MFMA_PH(0); PHASE_END; \
    /* P2 */ \
    RDA(fa[0][0], 0, 2, 0); RDA(fa[0][1], 0, 2, 1); \
    RDA(fa[1][0], 0, 3, 0); RDA(fa[1][1], 0, 3, 1); \
    STAGE_A(kb, 1, 49152); STAGE_B(kn, 0, 65536 + 0); \
    PHASE_MID; MFMA_PH(2); PHASE_END; \
    /* P3 */ \
    RDA(fa[0][0], 0, 4, 0); RDA(fa[0][1], 0, 4, 1); \
    RDA(fa[1][0], 0, 5, 0); RDA(fa[1][1], 0, 5, 1); \
    STAGE_B(kn, 1, 65536 + 16384); \
    PHASE_MID; MFMA_PH(4); PHASE_END; \
    /* P4 (gate) */ \
    RDA(fa[0][0], 0, 6, 0); RDA(fa[0][1], 0, 6, 1); \
    RDA(fa[1][0], 0, 7, 0); RDA(fa[1][1], 0, 7, 1); \
    PHASE_MID; MFMA_PH(6); G4; \
    /* P5: all fb(buf1) + fa m0-1 */ \
    RDA(fa[0][0], 1, 0, 0); RDA(fa[0][1], 1, 0, 1); \
    RDA(fa[1][0], 1, 1, 0); RDA(fa[1][1], 1, 1, 1); \
    RDB(fb[0][0], 1, 0, 0); RDB(fb[0][1], 1, 0, 1); \
    RDB(fb[1][0], 1, 1, 0); RDB(fb[1][1], 1, 1, 1); \
    RDB(fb[2][0], 1, 2, 0); RDB(fb[2][1], 1, 2, 1); \
    RDB(fb[3][0], 1, 3, 0); RDB(fb[3][1], 1, 3, 1); \
    STAGE_A(kn, 0, 0); \
    PHASE_MID; MFMA_PH(0); PHASE_END; \
    /* P6 */ \
    RDA(fa[0][0], 1, 2, 0); RDA(fa[0][1], 1, 2, 1); \
    RDA(fa[1][0], 1, 3, 0); RDA(fa[1][1], 1, 3, 1); \
    STAGE_A(kn, 1, 16384); STAGE_B(kn2, 0, 65536 + 32768); \
    PHASE_MID; MFMA_PH(2); PHASE_END; \
    /* P7 */ \
    RDA(fa[0][0], 1, 4, 0); RDA(fa[0][1], 1, 4, 1); \
    RDA(fa[1][0], 1, 5, 0); RDA(fa[1][1], 1, 5, 1); \
    STAGE_B(kn2, 1, 65536 + 49152); \
    PHASE_MID; MFMA_PH(4); PHASE_END; \
    /* P8 (gate) */ \
    RDA(fa[0][0], 1, 6, 0); RDA(fa[0][1], 1, 6, 1); \
    RDA(fa[1][0], 1, 7, 0); RDA(fa[1][1], 1, 7, 1); \
    PHASE_MID; MFMA_PH(6); G8; \
  } while (0)

  ITERN(1, 2, 3, PHASE_END_V4, PHASE_END_V4);
  ITERN(3, 4, 5, PHASE_END_V4, PHASE_END_V4);
  ITERN(5, 6, 7, PHASE_END_V4, PHASE_END_V4);
  ITERN(7, 8, 9, PHASE_END_V0, PHASE_END);

  // ---- epilogue: overlay reductions into staging LDS ----
  __syncthreads();
  float* fo = (float*)lds;
  int* lab = (int*)(fo + 3072);   // labR[256] | labC[256]
  if (tid < 256) lab[tid] = labels[rowA0 + tid];
  else           lab[tid] = labels[rowB0 + (tid - 256)];
  __syncthreads();

  float ecol[4] = {}, pcol[4] = {};
  int lc[4];
  #pragma unroll
  for (int n = 0; n < 4; ++n) lc[n] = lab[256 + wn * 64 + n * 16 + l15];

  #pragma unroll
  for (int m = 0; m < 8; ++m) {
    #pragma unroll
    for (int r = 0; r < 4; ++r) {
      int rowl = wm * 128 + m * 16 + ((lane >> 4) << 2) + r;
      int lrv = lab[rowl];
      float e = 0.0f, p = 0.0f;
      #pragma unroll
      for (int n = 0; n < 4; ++n) {
        float s = acc[m][n][r] * INVT;
        float ex = __expf(s);
        float pm = (lrv == lc[n]) ? s : 0.0f;
        e += ex; p += pm; ecol[n] += ex; pcol[n] += pm;
      }
      #pragma unroll
      for (int msk = 1; msk < 16; msk <<= 1) {
        e += __shfl_xor(e, msk); p += __shfl_xor(p, msk);
      }
      if (l15 == 0) {
        fo[wn * 256 + rowl] = e;
        fo[1024 + wn * 256 + rowl] = p;
      }
    }
  }
  if (offdiag) {
    #pragma unroll
    for (int n = 0; n < 4; ++n) {
      float e = ecol[n], p = pcol[n];
      e += __shfl_xor(e, 16); e += __shfl_xor(e, 32);
      p += __shfl_xor(p, 16); p += __shfl_xor(p, 32);
      if (lane < 16) {
        int c = wn * 64 + n * 16 + l15;
        fo[2048 + wm * 256 + c] = e;
        fo[2560 + wm * 256 + c] = p;
      }
    }
  }
  __syncthreads();
  if (tid < 256) {
    float e = fo[tid] + fo[256 + tid] + fo[512 + tid] + fo[768 + tid];
    float p = fo[1024 + tid] + fo[1280 + tid] + fo[1536 + tid] + fo[1792 + tid];
    size_t off = (size_t)bx * N + rowA0 + tid;
    part_e[off] = e; part_p[off] = p;
  } else if (offdiag) {
    int c = tid - 256;
    float e = fo[2048 + c] + fo[2304 + c];
    float p = fo[2560 + c] + fo[2816 + c];
    size_t off = (size_t)by * N + rowB0 + c;
    part_e[off] = e; part_p[off] = p;
  }
}

// ---------------- kernel 4: per-row loss + atomic mean ----------------
__global__ __launch_bounds__(256) void k_final(
    const float* __restrict__ part_e, const float* __restrict__ part_p,
    const int* __restrict__ labels, const int* __restrict__ hist,
    float* __restrict__ out) {
  const int i = blockIdx.x * 256 + threadIdx.x;
  float e = 0.0f, p = 0.0f;
  #pragma unroll 8
  for (int cb = 0; cb < NCB; ++cb) {
    e += part_e[(size_t)cb * N + i];
    p += part_p[(size_t)cb * N + i];
  }
  float cnt = (float)hist[labels[i]];
  float li = logf(e) - p / cnt;
  #pragma unroll
  for (int m = 1; m < 64; m <<= 1) li += __shfl_xor(li, m);
  __shared__ float red[4];
  if ((threadIdx.x & 63) == 0) red[threadIdx.x >> 6] = li;
  __syncthreads();
  if (threadIdx.x == 0)
    atomicAdd(out, (red[0] + red[1] + red[2] + red[3]) * (1.0f / (float)N));
}

extern "C" void kernel_launch(void* const* d_in, const int* in_sizes, int n_in,
                              void* d_out, int out_size, void* d_ws, size_t ws_size,
                              hipStream_t stream) {
  const float* x = (const float*)d_in[0];
  const int* labels = (const int*)d_in[1];
  float* out = (float*)d_out;
  char* ws = (char*)d_ws;

  unsigned short* fb = (unsigned short*)ws;                 // 8 MB bf16 normalized
  float* part_e = (float*)(ws + (size_t)8 * 1024 * 1024);   // 1 MB (32 x 8192)
  float* part_p = (float*)(ws + (size_t)9 * 1024 * 1024);   // 1 MB
  int*   hist   = (int*)  (ws + (size_t)10 * 1024 * 1024);  // 512 B

  hipMemsetAsync(hist, 0, 512, stream);
  hipMemsetAsync(out, 0, sizeof(float), stream);
  k_normalize<<<N / 4, 256, 0, stream>>>(x, fb);
  k_hist<<<N / 256, 256, 0, stream>>>(labels, hist);
  k_gemm<<<NTRI, 512, 0, stream>>>(fb, labels, part_e, part_p);
  k_final<<<N / 256, 256, 0, stream>>>(part_e, part_p, labels, hist, out);
}

// Round 7
// 84.853 us; speedup vs baseline: 1.1594x; 1.1594x over previous
//
#include <hip/hip_runtime.h>
#include <hip/hip_bf16.h>

#define N 8192
#define D 512
#define BM 128
#define BN 128
#define BK 64
#define NCB (N / BN)   // 64 column blocks
#define NKT (D / BK)   // 8 K tiles
#define NTRI (NCB * (NCB + 1) / 2)  // 2080 upper-triangle blocks (2080 % 8 == 0)
#define INVT 14.285714285714286f

typedef __attribute__((ext_vector_type(8))) short bf16x8;
typedef __attribute__((ext_vector_type(4))) float f32x4;
typedef __attribute__((ext_vector_type(8))) unsigned short u16x8;

__device__ __forceinline__ unsigned short f2bf(float f) {
  __hip_bfloat16 h = __float2bfloat16(f);
  return *reinterpret_cast<unsigned short*>(&h);
}

// ---------------- kernel 1: L2-normalize rows, cast to bf16 ----------------
__global__ __launch_bounds__(256) void k_normalize(const float* __restrict__ x,
                                                   unsigned short* __restrict__ fb) {
  const int row = blockIdx.x * 4 + (threadIdx.x >> 6);
  const int lane = threadIdx.x & 63;
  const float* rp = x + (size_t)row * D + lane * 8;
  float4 v0 = *reinterpret_cast<const float4*>(rp);
  float4 v1 = *reinterpret_cast<const float4*>(rp + 4);
  float s = v0.x*v0.x + v0.y*v0.y + v0.z*v0.z + v0.w*v0.w
          + v1.x*v1.x + v1.y*v1.y + v1.z*v1.z + v1.w*v1.w;
  #pragma unroll
  for (int m = 1; m < 64; m <<= 1) s += __shfl_xor(s, m);
  float inv = 1.0f / fmaxf(sqrtf(s), 1e-12f);
  u16x8 o;
  o[0] = f2bf(v0.x*inv); o[1] = f2bf(v0.y*inv); o[2] = f2bf(v0.z*inv); o[3] = f2bf(v0.w*inv);
  o[4] = f2bf(v1.x*inv); o[5] = f2bf(v1.y*inv); o[6] = f2bf(v1.z*inv); o[7] = f2bf(v1.w*inv);
  *reinterpret_cast<u16x8*>(fb + (size_t)row * D + lane * 8) = o;
}

// ---------------- kernel 2: fused GEMM + exp-rowsum + masked-sum ----------------
// Proven R3 structure (56.6us, zero bank conflicts, no spills), plus XCD-chunked
// triangle swizzle: 2080 blocks = 8 chunks x 260; chunk c -> XCD c (blockIdx%8
// round-robins XCDs), so consecutive t within a chunk (mostly same bx B-panel)
// stay on one XCD's L2.  // R7: dispatch diet + T1 swizzle only; K-loop untouched.
#define GLOAD_LDS16(g, l) __builtin_amdgcn_global_load_lds( \
    (const __attribute__((address_space(1))) unsigned int*)(g), \
    (__attribute__((address_space(3))) unsigned int*)(l), 16, 0, 0)

__global__ __launch_bounds__(256, 3) void k_gemm(
    const unsigned short* __restrict__ fb, const int* __restrict__ labels,
    float* __restrict__ part_e, float* __restrict__ part_p) {
  __shared__ __align__(16) short As[BM * BK];
  __shared__ __align__(16) short Bs[BN * BK];
  __shared__ float e_part[2][BM];   // row-partials, indexed by wc
  __shared__ float p_part[2][BM];
  __shared__ float e_cpart[2][BN];  // col-partials, indexed by wr
  __shared__ float p_cpart[2][BN];
  __shared__ int labR[BM];
  __shared__ int labC[BN];

  const int tid = threadIdx.x;
  const int lane = tid & 63;
  const int w = tid >> 6;
  const int wr = w >> 1, wc = w & 1;

  // XCD-chunked bijective swizzle (NTRI % 8 == 0)
  const int b0 = blockIdx.x;
  const int t = (b0 & 7) * (NTRI / 8) + (b0 >> 3);

  // triangle index -> (bx, by), by <= bx
  int bx = (int)((sqrtf(8.0f * (float)t + 1.0f) - 1.0f) * 0.5f);
  while ((bx + 1) * (bx + 2) / 2 <= t) ++bx;
  while (bx * (bx + 1) / 2 > t) --bx;
  const int by = t - bx * (bx + 1) / 2;
  const bool offdiag = (bx != by);

  const int rowA0 = by * BM, rowB0 = bx * BN;

  if (tid < BM) labR[tid] = labels[rowA0 + tid];
  else          labC[tid - BM] = labels[rowB0 + (tid - BM)];

  f32x4 acc[4][4] = {};
  const int sslot = tid & 7;

  for (int kt = 0; kt < NKT; ++kt) {
    if (kt) __syncthreads();
    const int kbase = kt * BK;
    #pragma unroll
    for (int it = 0; it < 4; ++it) {
      int r = (it * 256 + tid) >> 3;
      int kcol = ((sslot ^ (r & 7)) << 3) + kbase;
      GLOAD_LDS16(fb + (size_t)(rowA0 + r) * D + kcol,
                  (char*)As + it * 4096 + w * 1024);
    }
    #pragma unroll
    for (int it = 0; it < 4; ++it) {
      int r = (it * 256 + tid) >> 3;
      int kcol = ((sslot ^ (r & 7)) << 3) + kbase;
      GLOAD_LDS16(fb + (size_t)(rowB0 + r) * D + kcol,
                  (char*)Bs + it * 4096 + w * 1024);
    }
    __syncthreads();

    #pragma unroll
    for (int kk = 0; kk < BK; kk += 32) {
      bf16x8 af[4], bg[4];
      #pragma unroll
      for (int m = 0; m < 4; ++m) {
        int ar = wr * 64 + m * 16 + (lane & 15);
        int kb = (kk + ((lane >> 4) << 3)) * 2;
        af[m] = *reinterpret_cast<const bf16x8*>(
            (const char*)As + ar * 128 + (kb ^ ((ar & 7) << 4)));
      }
      #pragma unroll
      for (int n = 0; n < 4; ++n) {
        int br = wc * 64 + n * 16 + (lane & 15);
        int kb = (kk + ((lane >> 4) << 3)) * 2;
        bg[n] = *reinterpret_cast<const bf16x8*>(
            (const char*)Bs + br * 128 + (kb ^ ((br & 7) << 4)));
      }
      #pragma unroll
      for (int m = 0; m < 4; ++m)
        #pragma unroll
        for (int n = 0; n < 4; ++n)
          acc[m][n] = __builtin_amdgcn_mfma_f32_16x16x32_bf16(af[m], bg[n], acc[m][n], 0, 0, 0);
    }
  }

  // ---- fused epilogue (low register pressure: scalar e/p per (m,r)) ----
  float ecol[4] = {};
  float pcol[4] = {};
  int lc[4];
  #pragma unroll
  for (int n = 0; n < 4; ++n)
    lc[n] = labC[wc * 64 + n * 16 + (lane & 15)];

  #pragma unroll
  for (int m = 0; m < 4; ++m)
    #pragma unroll
    for (int r = 0; r < 4; ++r) {
      int lrv = labR[wr * 64 + m * 16 + ((lane >> 4) << 2) + r];
      float e = 0.0f, p = 0.0f;
      #pragma unroll
      for (int n = 0; n < 4; ++n) {
        float s = acc[m][n][r] * INVT;
        float ex = __expf(s);
        float pm = (lrv == lc[n]) ? s : 0.0f;
        e += ex; p += pm;
        ecol[n] += ex; pcol[n] += pm;
      }
      #pragma unroll
      for (int msk = 1; msk < 16; msk <<= 1) {
        e += __shfl_xor(e, msk);
        p += __shfl_xor(p, msk);
      }
      if ((lane & 15) == 0) {
        int row = wr * 64 + m * 16 + ((lane >> 4) << 2) + r;
        e_part[wc][row] = e;
        p_part[wc][row] = p;
      }
    }

  // col-partials: reduce across the 4 row-groups (lane>>4)
  if (offdiag) {
    #pragma unroll
    for (int n = 0; n < 4; ++n) {
      float e = ecol[n], p = pcol[n];
      e += __shfl_xor(e, 16); e += __shfl_xor(e, 32);
      p += __shfl_xor(p, 16); p += __shfl_xor(p, 32);
      if ((lane >> 4) == 0) {
        int c = wc * 64 + n * 16 + (lane & 15);
        e_cpart[wr][c] = e;
        p_cpart[wr][c] = p;
      }
    }
  }
  __syncthreads();

  if (tid < BM) {
    float e = e_part[0][tid] + e_part[1][tid];
    float p = p_part[0][tid] + p_part[1][tid];
    size_t off = (size_t)bx * N + rowA0 + tid;
    part_e[off] = e;
    part_p[off] = p;
  } else if (offdiag) {
    int c = tid - BM;
    float e = e_cpart[0][c] + e_cpart[1][c];
    float p = p_cpart[0][c] + p_cpart[1][c];
    size_t off = (size_t)by * N + rowB0 + c;
    part_e[off] = e;
    part_p[off] = p;
  }
}

// ---------------- kernel 3: per-row loss + block partial sums ----------------
// Builds the label histogram per-block in LDS (no k_hist kernel, no memset).
__global__ __launch_bounds__(256) void k_final(
    const float* __restrict__ part_e, const float* __restrict__ part_p,
    const int* __restrict__ labels, float* __restrict__ bsum) {
  __shared__ int h[128];
  const int tid = threadIdx.x;
  if (tid < 128) h[tid] = 0;
  __syncthreads();
  for (int j = tid; j < N; j += 256) atomicAdd(&h[labels[j]], 1);

  const int i = blockIdx.x * 256 + tid;
  float e = 0.0f, p = 0.0f;
  #pragma unroll 8
  for (int cb = 0; cb < NCB; ++cb) {
    e += part_e[(size_t)cb * N + i];
    p += part_p[(size_t)cb * N + i];
  }
  __syncthreads();
  float cnt = (float)h[labels[i]];
  float li = logf(e) - p / cnt;
  #pragma unroll
  for (int m = 1; m < 64; m <<= 1) li += __shfl_xor(li, m);
  __shared__ float red[4];
  if ((tid & 63) == 0) red[tid >> 6] = li;
  __syncthreads();
  if (tid == 0) bsum[blockIdx.x] = red[0] + red[1] + red[2] + red[3];
}

// ---------------- kernel 4: final scalar (overwrites out; no memset) --------
__global__ void k_sum(const float* __restrict__ bsum, float* __restrict__ out) {
  float v = (threadIdx.x < (N / 256)) ? bsum[threadIdx.x] : 0.0f;
  #pragma unroll
  for (int m = 1; m < 64; m <<= 1) v += __shfl_xor(v, m);
  if (threadIdx.x == 0) out[0] = v * (1.0f / (float)N);
}

extern "C" void kernel_launch(void* const* d_in, const int* in_sizes, int n_in,
                              void* d_out, int out_size, void* d_ws, size_t ws_size,
                              hipStream_t stream) {
  const float* x = (const float*)d_in[0];
  const int* labels = (const int*)d_in[1];
  float* out = (float*)d_out;
  char* ws = (char*)d_ws;

  unsigned short* fb = (unsigned short*)ws;                       // 8 MB bf16 normalized
  float* part_e = (float*)(ws + (size_t)8  * 1024 * 1024);        // 2 MB (64 x 8192)
  float* part_p = (float*)(ws + (size_t)10 * 1024 * 1024);        // 2 MB
  float* bsum   = (float*)(ws + (size_t)12 * 1024 * 1024);        // 128 B

  k_normalize<<<N / 4, 256, 0, stream>>>(x, fb);
  k_gemm<<<NTRI, 256, 0, stream>>>(fb, labels, part_e, part_p);
  k_final<<<N / 256, 256, 0, stream>>>(part_e, part_p, labels, bsum);
  k_sum<<<1, 64, 0, stream>>>(bsum, out);
}